// Round 10
// baseline (430.770 us; speedup 1.0000x reference)
//
#include <hip/hip_runtime.h>
#include <hip/hip_bf16.h>
#include <cmath>

// ---------------------------------------------------------------------------
// Problem constants (B=1, T=2048, D=768, H=4, N=25600, KD=128, HQ=512,
// HID_A=44, HID_S=1024, KNN=16)
// ---------------------------------------------------------------------------
#define NEG_INF (-3.402823466e38f)
#define SPLITS 32          // N-splits per head
#define SPN    800         // experts per split
#define NSUB   50          // 16-expert subtiles per split (800/16)

typedef __attribute__((ext_vector_type(8))) short s16x8;   // 8 bf16 (4 VGPRs)
typedef __attribute__((ext_vector_type(4))) float f32x4;   // MFMA C/D frag

__device__ __forceinline__ unsigned short f2bf(float f) {
    union { float f; unsigned u; } v; v.f = f;
    unsigned u = v.u;
    u += 0x7fffu + ((u >> 16) & 1u);   // round-to-nearest-even
    return (unsigned short)(u >> 16);
}

// ---------------------------------------------------------------------------
// One fused fp32->bf16 convert for ALL tensors + fused row-sum of x.
// ---------------------------------------------------------------------------
__global__ __launch_bounds__(256) void cvt_all_kernel(
        const float* __restrict__ s0, const float* __restrict__ s1,
        const float* __restrict__ s2, const float* __restrict__ s3,
        const float* __restrict__ s4, const float* __restrict__ keys,
        unsigned short* __restrict__ dst, float* __restrict__ sumx) {
    int i = blockIdx.x * 256 + threadIdx.x;
    if (i >= 4358144) return;                      // 1081344 small + 3276800 keys
    const float* src; int base;
    if      (i < 393216)  { src = s0;   base = 0; }
    else if (i < 491520)  { src = s1;   base = 393216; }
    else if (i < 688128)  { src = s2;   base = 491520; }
    else if (i < 884736)  { src = s3;   base = 688128; }
    else if (i < 1081344) { src = s4;   base = 884736; }
    else                  { src = keys; base = 1081344; }
    float4 f = ((const float4*)src)[i - base];
    ushort4 o;
    o.x = f2bf(f.x); o.y = f2bf(f.y); o.z = f2bf(f.z); o.w = f2bf(f.w);
    ((ushort4*)dst)[i] = o;
    if (i < 393216) {                              // x region: fused row sum
        float s = f.x + f.y + f.z + f.w;
        #pragma unroll
        for (int off = 32; off > 0; off >>= 1) s += __shfl_down(s, off);
        if ((threadIdx.x & 63) == 0) atomicAdd(&sumx[i / 192], s);
    }
}

// ---------------------------------------------------------------------------
// GEMM  C = A @ W^T  (generic, 64x64 tile, BK=64). EPI 0: q-proj epilogue
// (+bq, BatchNorm) -> bf16. EPI 2: +combsum[m] -> fp32 (legacy path only).
// ---------------------------------------------------------------------------
template <int EPI>
__global__ __launch_bounds__(256) void gemm_nt(
        const unsigned short* __restrict__ A, const unsigned short* __restrict__ W,
        int M, int N, int K,
        float* __restrict__ outF, unsigned short* __restrict__ outB,
        const float* __restrict__ p0, const float* __restrict__ p1,
        const float* __restrict__ p2, const float* __restrict__ p3,
        const float* __restrict__ p4) {
    __shared__ alignas(16) short As[64][72];
    __shared__ alignas(16) short Ws[64][72];
    const int tid = threadIdx.x;
    const int m0 = blockIdx.x * 64, n0 = blockIdx.y * 64;
    const int wv = tid >> 6, lane = tid & 63;
    const int wr = wv >> 1, wc = wv & 1;
    const int lr = lane & 15, lq = lane >> 4;
    f32x4 acc[2][2];
    #pragma unroll
    for (int i = 0; i < 2; ++i)
        #pragma unroll
        for (int j = 0; j < 2; ++j) acc[i][j] = (f32x4){0.f, 0.f, 0.f, 0.f};

    for (int kb = 0; kb < K; kb += 64) {
        #pragma unroll
        for (int it = 0; it < 2; ++it) {
            int chunk = tid + it * 256;
            int row = chunk >> 3, c8 = (chunk & 7) * 8;
            *(s16x8*)&As[row][c8] = *(const s16x8*)(A + (size_t)(m0 + row) * K + kb + c8);
            *(s16x8*)&Ws[row][c8] = *(const s16x8*)(W + (size_t)(n0 + row) * K + kb + c8);
        }
        __syncthreads();
        #pragma unroll
        for (int ks = 0; ks < 2; ++ks) {
            const int k0 = ks * 32 + lq * 8;
            #pragma unroll
            for (int rt = 0; rt < 2; ++rt) {
                s16x8 a = *(const s16x8*)&As[wr * 32 + rt * 16 + lr][k0];
                #pragma unroll
                for (int ct = 0; ct < 2; ++ct) {
                    s16x8 b = *(const s16x8*)&Ws[wc * 32 + ct * 16 + lr][k0];
                    acc[rt][ct] = __builtin_amdgcn_mfma_f32_16x16x32_bf16(a, b, acc[rt][ct], 0, 0, 0);
                }
            }
        }
        __syncthreads();
    }
    // C/D layout: col = lane&15, row = (lane>>4)*4 + r  [verified m89/m91]
    #pragma unroll
    for (int rt = 0; rt < 2; ++rt)
        #pragma unroll
        for (int ct = 0; ct < 2; ++ct)
            #pragma unroll
            for (int r = 0; r < 4; ++r) {
                int m = m0 + wr * 32 + rt * 16 + lq * 4 + r;
                int n = n0 + wc * 32 + ct * 16 + lr;
                float v = acc[rt][ct][r];
                if (EPI == 0) {
                    float q = v + p0[n];
                    q = (q - p3[n]) * rsqrtf(p4[n] + 1e-5f) * p1[n] + p2[n];
                    outB[(size_t)m * N + n] = f2bf(q);
                } else {
                    outF[(size_t)m * N + n] = v + p0[m];
                }
            }
}

// ---------------------------------------------------------------------------
// SwiGLU-up body (h = silu(x@W1^T)*(x@W3^T) -> bf16, 2048x1024, K=768).
// sb in [0,512): m0=(sb&31)*64, n0=(sb>>5)*64. smem >= 27648 B.
// ---------------------------------------------------------------------------
__device__ __forceinline__ void swiglu_body(
        int sb, int tid, const unsigned short* __restrict__ A,
        const unsigned short* __restrict__ W1, const unsigned short* __restrict__ W3,
        unsigned short* __restrict__ outB, char* smem) {
    short (*As)[72]  = (short(*)[72])smem;            //  9216 B
    short (*W1s)[72] = (short(*)[72])(smem + 9216);   //  9216 B
    short (*W3s)[72] = (short(*)[72])(smem + 18432);  //  9216 B
    const int m0 = (sb & 31) * 64, n0 = (sb >> 5) * 64;
    const int wv = tid >> 6, lane = tid & 63;
    const int wr = wv >> 1, wc = wv & 1;
    const int lr = lane & 15, lq = lane >> 4;
    f32x4 acc1[2][2], acc3[2][2];
    #pragma unroll
    for (int i = 0; i < 2; ++i)
        #pragma unroll
        for (int j = 0; j < 2; ++j) {
            acc1[i][j] = (f32x4){0.f, 0.f, 0.f, 0.f};
            acc3[i][j] = (f32x4){0.f, 0.f, 0.f, 0.f};
        }
    for (int kb = 0; kb < 768; kb += 64) {
        #pragma unroll
        for (int it = 0; it < 2; ++it) {
            int chunk = tid + it * 256;
            int row = chunk >> 3, c8 = (chunk & 7) * 8;
            *(s16x8*)&As[row][c8]  = *(const s16x8*)(A  + (size_t)(m0 + row) * 768 + kb + c8);
            *(s16x8*)&W1s[row][c8] = *(const s16x8*)(W1 + (size_t)(n0 + row) * 768 + kb + c8);
            *(s16x8*)&W3s[row][c8] = *(const s16x8*)(W3 + (size_t)(n0 + row) * 768 + kb + c8);
        }
        __syncthreads();
        #pragma unroll
        for (int ks = 0; ks < 2; ++ks) {
            const int k0 = ks * 32 + lq * 8;
            #pragma unroll
            for (int rt = 0; rt < 2; ++rt) {
                s16x8 a = *(const s16x8*)&As[wr * 32 + rt * 16 + lr][k0];
                #pragma unroll
                for (int ct = 0; ct < 2; ++ct) {
                    s16x8 b1 = *(const s16x8*)&W1s[wc * 32 + ct * 16 + lr][k0];
                    s16x8 b3 = *(const s16x8*)&W3s[wc * 32 + ct * 16 + lr][k0];
                    acc1[rt][ct] = __builtin_amdgcn_mfma_f32_16x16x32_bf16(a, b1, acc1[rt][ct], 0, 0, 0);
                    acc3[rt][ct] = __builtin_amdgcn_mfma_f32_16x16x32_bf16(a, b3, acc3[rt][ct], 0, 0, 0);
                }
            }
        }
        __syncthreads();
    }
    #pragma unroll
    for (int rt = 0; rt < 2; ++rt)
        #pragma unroll
        for (int ct = 0; ct < 2; ++ct)
            #pragma unroll
            for (int r = 0; r < 4; ++r) {
                int m = m0 + wr * 32 + rt * 16 + lq * 4 + r;
                int n = n0 + wc * 32 + ct * 16 + lr;
                float u1 = acc1[rt][ct][r], u3 = acc3[rt][ct][r];
                float hv = u1 / (1.f + expf(-u1)) * u3;
                outB[(size_t)m * 1024 + n] = f2bf(hv);
            }
}

// ---------------------------------------------------------------------------
// Down-proj body, RAW (out = h @ W2^T, 2048x768, K=1024; combsum added later
// by finalize_out). sb in [0,384): m0=(sb&31)*64, n0=(sb>>5)*64. smem>=18432.
// ---------------------------------------------------------------------------
__device__ __forceinline__ void down_body(
        int sb, int tid, const unsigned short* __restrict__ A,
        const unsigned short* __restrict__ W, float* __restrict__ outF,
        char* smem) {
    short (*As)[72] = (short(*)[72])smem;             //  9216 B
    short (*Ws)[72] = (short(*)[72])(smem + 9216);    //  9216 B
    const int m0 = (sb & 31) * 64, n0 = (sb >> 5) * 64;
    const int wv = tid >> 6, lane = tid & 63;
    const int wr = wv >> 1, wc = wv & 1;
    const int lr = lane & 15, lq = lane >> 4;
    f32x4 acc[2][2];
    #pragma unroll
    for (int i = 0; i < 2; ++i)
        #pragma unroll
        for (int j = 0; j < 2; ++j) acc[i][j] = (f32x4){0.f, 0.f, 0.f, 0.f};
    for (int kb = 0; kb < 1024; kb += 64) {
        #pragma unroll
        for (int it = 0; it < 2; ++it) {
            int chunk = tid + it * 256;
            int row = chunk >> 3, c8 = (chunk & 7) * 8;
            *(s16x8*)&As[row][c8] = *(const s16x8*)(A + (size_t)(m0 + row) * 1024 + kb + c8);
            *(s16x8*)&Ws[row][c8] = *(const s16x8*)(W + (size_t)(n0 + row) * 1024 + kb + c8);
        }
        __syncthreads();
        #pragma unroll
        for (int ks = 0; ks < 2; ++ks) {
            const int k0 = ks * 32 + lq * 8;
            #pragma unroll
            for (int rt = 0; rt < 2; ++rt) {
                s16x8 a = *(const s16x8*)&As[wr * 32 + rt * 16 + lr][k0];
                #pragma unroll
                for (int ct = 0; ct < 2; ++ct) {
                    s16x8 b = *(const s16x8*)&Ws[wc * 32 + ct * 16 + lr][k0];
                    acc[rt][ct] = __builtin_amdgcn_mfma_f32_16x16x32_bf16(a, b, acc[rt][ct], 0, 0, 0);
                }
            }
        }
        __syncthreads();
    }
    #pragma unroll
    for (int rt = 0; rt < 2; ++rt)
        #pragma unroll
        for (int ct = 0; ct < 2; ++ct)
            #pragma unroll
            for (int r = 0; r < 4; ++r) {
                int m = m0 + wr * 32 + rt * 16 + lq * 4 + r;
                int n = n0 + wc * 32 + ct * 16 + lr;
                outF[(size_t)m * 768 + n] = acc[rt][ct][r];
            }
}

// ---------------------------------------------------------------------------
// Score-pass body, r17: DIRECT-GLOBAL K loads with REGISTER PING-PONG
// pipelining (no LDS, no __syncthreads). r16's direct version serialized
// load->MFMA per subtile (no prefetch distance -> 122us); this restores the
// anchor's one-subtile-ahead prefetch schedule, minus the LDS hop and minus
// the 50 barrier+vmcnt(0) drains:
//   loop g (25 iters, unroll 1):  kb <- subtile 2g+1 ; MFMA(ka, s=2g) ;
//                                 ka <- subtile 2g+2 ; MFMA(kb, s=2g+1)
// Each 4-load batch has a 16-MFMA (~78 cyc) window + reduction VALU before
// its first use. Scores bitwise-identical across passes (same MFMA order and
// inputs) -> theta bound unchanged. Expert mapping n = nb0+s*16+lq*4+r and
// cell = (sp,lq) identical to the anchor.
// Regs ~140 -> __launch_bounds__(256,3) (cap ~170, no forced spill; staged
// anchor also ran 3 blocks/CU). #pragma unroll 1 pins the loop (r10 lesson).
// VALIDITY: WRITE_SIZE ~16MB (no spill); falsifier: megaB >= 82us -> revert
// to r15 staged body.
// ---------------------------------------------------------------------------
template <int PASS>
__device__ __forceinline__ void score_body(
        int b, int tid,
        const unsigned short* __restrict__ Q, const unsigned short* __restrict__ Kt,
        float* __restrict__ maxbuf, const float* __restrict__ theta,
        int* __restrict__ cnt, float2* __restrict__ buf) {
    const int tile = b >> 7;                     // 128 = 4 heads x 32 splits
    const int hsp = b & 127;
    const int h = hsp >> 5, sp = hsp & 31;
    const int w = tid >> 6, lane = tid & 63;
    const int lr = lane & 15, lq = lane >> 4;
    const int t0 = tile * 256 + w * 64;
    const int nb0 = sp * SPN;

    s16x8 qf[4][4];
    #pragma unroll
    for (int tt = 0; tt < 4; ++tt) {
        const unsigned short* qp = Q + (size_t)(t0 + tt * 16 + lr) * 512 + h * 128 + lq * 8;
        #pragma unroll
        for (int ks = 0; ks < 4; ++ks) qf[tt][ks] = *(const s16x8*)(qp + ks * 32);
    }

    float runmax[4] = {NEG_INF, NEG_INF, NEG_INF, NEG_INF};
    float th[4];
    if (PASS == 2) {
        #pragma unroll
        for (int tt = 0; tt < 4; ++tt) th[tt] = theta[(t0 + tt * 16 + lr) * 4 + h];
    }

    // per-lane fragment base: row (nb0 + lr), col lq*8; subtile s = +2048 bf16.
    const unsigned short* kp0 =
        Kt + ((size_t)h * 25600 + nb0 + lr) * 128 + lq * 8;

    // load subtile s's A-fragments (4 x s16x8, statically indexed -> regs)
    auto lda = [&](int s, s16x8* k) {
        const unsigned short* kp = kp0 + (size_t)s * 2048;
        k[0] = *(const s16x8*)(kp);
        k[1] = *(const s16x8*)(kp + 32);
        k[2] = *(const s16x8*)(kp + 64);
        k[3] = *(const s16x8*)(kp + 96);
    };
    // 16 MFMAs + PASS-specific reduction for subtile s
    auto compute = [&](const s16x8* k, int s) {
        f32x4 acc[4];
        #pragma unroll
        for (int tt = 0; tt < 4; ++tt) acc[tt] = (f32x4){0.f, 0.f, 0.f, 0.f};
        #pragma unroll
        for (int ks = 0; ks < 4; ++ks)
            #pragma unroll
            for (int tt = 0; tt < 4; ++tt)
                acc[tt] = __builtin_amdgcn_mfma_f32_16x16x32_bf16(k[ks], qf[tt][ks], acc[tt], 0, 0, 0);
        if (PASS == 1) {
            #pragma unroll
            for (int tt = 0; tt < 4; ++tt) {
                float m0 = fmaxf(fmaxf(acc[tt][0], acc[tt][1]),
                                 fmaxf(acc[tt][2], acc[tt][3]));
                runmax[tt] = fmaxf(runmax[tt], m0);
            }
        } else {
            const int nb = nb0 + s * 16;
            #pragma unroll
            for (int tt = 0; tt < 4; ++tt) {
                float m0 = fmaxf(fmaxf(acc[tt][0], acc[tt][1]),
                                 fmaxf(acc[tt][2], acc[tt][3]));
                if (m0 >= th[tt]) {
                    int g4 = (t0 + tt * 16 + lr) * 4 + h;
                    #pragma unroll
                    for (int r = 0; r < 4; ++r) {
                        if (acc[tt][r] >= th[tt]) {
                            int n = nb + lq * 4 + r;   // D row = lq*4+r
                            int pos = atomicAdd(&cnt[g4], 1);
                            if (pos < 64) {
                                float2 e; e.x = acc[tt][r]; e.y = __int_as_float(n);
                                buf[(size_t)g4 * 64 + pos] = e;
                            }
                        }
                    }
                }
            }
        }
    };

    s16x8 ka[4], kb[4];
    lda(0, ka);                                  // prologue
    #pragma unroll 1
    for (int g = 0; g < NSUB / 2; ++g) {         // 25 iters, 2 subtiles each
        lda(2 * g + 1, kb);                      // prefetch odd subtile
        compute(ka, 2 * g);                      // 16-MFMA window covers kb
        if (g < NSUB / 2 - 1) lda(2 * g + 2, ka);// prefetch next even subtile
        compute(kb, 2 * g + 1);                  // window covers ka
    }

    if (PASS == 1) {
        #pragma unroll
        for (int tt = 0; tt < 4; ++tt)
            maxbuf[(size_t)((t0 + tt * 16 + lr) * 4 + h) * 128 + sp * 4 + lq] = runmax[tt];
    }
}

// ---------------------------------------------------------------------------
// Standalone score pass (legacy path).
// ---------------------------------------------------------------------------
template <int PASS>
__global__ __launch_bounds__(256, 3) void score_pass_kernel(
        const unsigned short* __restrict__ Q, const unsigned short* __restrict__ Kt,
        float* __restrict__ maxbuf, const float* __restrict__ theta,
        int* __restrict__ cnt, float2* __restrict__ buf) {
    score_body<PASS>(blockIdx.x, threadIdx.x, Q, Kt, maxbuf, theta, cnt, buf);
}

// ---------------------------------------------------------------------------
// Fused mega-kernels: dense-GEMM blocks FIRST, score blocks after.
// Offsets 512/384 are =0 mod 8 -> score slab->XCD co-location preserved.
// ---------------------------------------------------------------------------
__global__ __launch_bounds__(256, 3) void megaA_kernel(   // swiglu(512) + score1(1024)
        const unsigned short* __restrict__ xb, const unsigned short* __restrict__ w1,
        const unsigned short* __restrict__ w3, unsigned short* __restrict__ hb,
        const unsigned short* __restrict__ Q, const unsigned short* __restrict__ Kt,
        float* __restrict__ maxbuf) {
    __shared__ alignas(16) char smem[27648];
    if (blockIdx.x < 512)
        swiglu_body(blockIdx.x, threadIdx.x, xb, w1, w3, hb, smem);
    else
        score_body<1>(blockIdx.x - 512, threadIdx.x, Q, Kt, maxbuf,
                      nullptr, nullptr, nullptr);
}

__global__ __launch_bounds__(256, 3) void megaB_kernel(   // down(384) + score2(1024)
        const unsigned short* __restrict__ hb, const unsigned short* __restrict__ w2,
        float* __restrict__ outF,
        const unsigned short* __restrict__ Q, const unsigned short* __restrict__ Kt,
        const float* __restrict__ theta, int* __restrict__ cnt,
        float2* __restrict__ buf) {
    __shared__ alignas(16) char smem[18432];
    if (blockIdx.x < 384)
        down_body(blockIdx.x, threadIdx.x, hb, w2, outF, smem);
    else
        score_body<2>(blockIdx.x - 384, threadIdx.x, Q, Kt, nullptr,
                      theta, cnt, buf);
}

// ---------------------------------------------------------------------------
// theta = 16th-largest of the 128 cell maxima per (t,h).
// ---------------------------------------------------------------------------
__global__ __launch_bounds__(64) void theta_kernel(
        const float* __restrict__ maxbuf, float* __restrict__ theta) {
    int g = blockIdx.x * 64 + threadIdx.x;
    if (g >= 8192) return;
    const float* mb = maxbuf + (size_t)g * 128;
    float s[16];
    #pragma unroll
    for (int i = 0; i < 16; ++i) s[i] = NEG_INF;
    for (int j = 0; j < 128; ++j) {
        float v = mb[j];
        if (v > s[15]) {
            #pragma unroll
            for (int i = 15; i > 0; --i)
                s[i] = (v > s[i - 1]) ? s[i - 1] : ((v > s[i]) ? v : s[i]);
            s[0] = (v > s[0]) ? v : s[0];
        }
    }
    theta[g] = s[15];
}

// ---------------------------------------------------------------------------
// Finalize. Block = token t (4 waves = 4 heads). Exact top-16 via rank,
// softmax, tiny MLP (reassociated). FUSE_OUT=1: block-reduce 4 head contribs
// and add to out[t][:] (out holds raw down-proj). FUSE_OUT=0: legacy.
// ---------------------------------------------------------------------------
template <int FUSE_OUT>
__global__ __launch_bounds__(256) void finalize_kernel(
        const int* __restrict__ cnt, const float2* __restrict__ buf,
        const float* __restrict__ sumx,
        const float* __restrict__ wdown, const float* __restrict__ wup,
        const float* __restrict__ aw1, const float* __restrict__ aw2,
        const float* __restrict__ aw3, float* __restrict__ combsum,
        float* __restrict__ out) {
    __shared__ float zsh[4][16];
    __shared__ float wsh[4][16];
    __shared__ float csh[4];
    const int wv = threadIdx.x >> 6, lane = threadIdx.x & 63;
    const int t = blockIdx.x;
    const int g = t * 4 + wv;
    int c = cnt[g]; c = (c > 64) ? 64 : c;       // >=16 guaranteed by theta

    float v = NEG_INF; int n = 0x7fffffff;
    if (lane < c) {
        float2 e = buf[(size_t)g * 64 + lane];
        v = e.x; n = __float_as_int(e.y);
    }
    int r = 0;
    for (int i = 0; i < c; ++i) {
        float vi = __shfl(v, i);
        int   ni = __shfl(n, i);
        r += ((vi > v) || (vi == v && ni < n)) ? 1 : 0;
    }
    float m = v;
    #pragma unroll
    for (int off = 32; off > 0; off >>= 1) m = fmaxf(m, __shfl_xor(m, off));
    const bool sel = (lane < c) && (r < 16);
    float e = sel ? expf(v - m) : 0.f;
    float den = e;
    #pragma unroll
    for (int off = 32; off > 0; off >>= 1) den += __shfl_xor(den, off);
    if (sel) {
        zsh[wv][r] = sumx[t] * wdown[n];
        wsh[wv][r] = (e / den) * wup[n];
    }
    __syncthreads();
    float contrib = 0.f;
    if (lane < 44) {
        float u1 = 0.f, u3 = 0.f, cj = 0.f;
        #pragma unroll
        for (int k = 0; k < 16; ++k) {
            float zk = zsh[wv][k];
            u1 += zk * aw1[lane * 16 + k];
            u3 += zk * aw3[lane * 16 + k];
            cj += wsh[wv][k] * aw2[k * 44 + lane];
        }
        float gj = u1 / (1.f + expf(-u1)) * u3;
        contrib = gj * cj;
    }
    #pragma unroll
    for (int off = 32; off > 0; off >>= 1) contrib += __shfl_xor(contrib, off);
    if (FUSE_OUT) {
        if (lane == 0) csh[wv] = contrib;
        __syncthreads();
        float comb = csh[0] + csh[1] + csh[2] + csh[3];
        float* orow = out + (size_t)t * 768;
        #pragma unroll
        for (int i = 0; i < 3; ++i) orow[threadIdx.x + i * 256] += comb;
    } else {
        if (lane == 0) atomicAdd(&combsum[t], contrib);
    }
}

// ---------------------------------------------------------------------------
// Legacy standalone SwiGLU (fallback path).
// ---------------------------------------------------------------------------
__global__ __launch_bounds__(256) void gemm_swiglu_kernel(
        const unsigned short* __restrict__ A, const unsigned short* __restrict__ W1,
        const unsigned short* __restrict__ W3, unsigned short* __restrict__ outB) {
    __shared__ alignas(16) char smem[27648];
    swiglu_body(blockIdx.x, threadIdx.x, A, W1, W3, outB, smem);
}

// ---------------------------------------------------------------------------
// Host launch
// ---------------------------------------------------------------------------
extern "C" void kernel_launch(void* const* d_in, const int* in_sizes, int n_in,
                              void* d_out, int out_size, void* d_ws, size_t ws_size,
                              hipStream_t stream) {
    const float* x     = (const float*)d_in[0];
    const float* wq    = (const float*)d_in[1];
    const float* bq    = (const float*)d_in[2];
    const float* gamma = (const float*)d_in[3];
    const float* beta  = (const float*)d_in[4];
    const float* mean  = (const float*)d_in[5];
    const float* var   = (const float*)d_in[6];
    const float* keys  = (const float*)d_in[7];
    const float* wdown = (const float*)d_in[8];
    const float* wup   = (const float*)d_in[9];
    const float* aw1   = (const float*)d_in[10];
    const float* aw2   = (const float*)d_in[11];
    const float* aw3   = (const float*)d_in[12];
    const float* sw1   = (const float*)d_in[13];
    const float* sw2   = (const float*)d_in[14];
    const float* sw3   = (const float*)d_in[15];
    float* out = (float*)d_out;

    char* ws = (char*)d_ws;
    unsigned short* x_b    = (unsigned short*)(ws + 0);         // 3,145,728 B
    unsigned short* wq_b   = (unsigned short*)(ws + 3145728);   //   786,432
    unsigned short* sw1_b  = (unsigned short*)(ws + 3932160);   // 1,572,864
    unsigned short* sw3_b  = (unsigned short*)(ws + 5505024);   // 1,572,864
    unsigned short* sw2_b  = (unsigned short*)(ws + 7077888);   // 1,572,864
    unsigned short* keys_b = (unsigned short*)(ws + 8650752);   // 26,214,400
    unsigned short* q_b    = (unsigned short*)(ws + 34865152);  // 2,097,152
    float* sumx    = (float*)(ws + 36962304);                   //     8,192 }
    float* theta   = (float*)(ws + 36970496);                   //    32,768 } one
    float* combsum = (float*)(ws + 37003264);                   //     8,192 } memset
    int*   cnt     = (int*)  (ws + 37011456);                   //    32,768 }
    // R1 (4 MB): maxbuf (A-phase) -> buf (B-phase). h_b separate in fused
    // path (lives across A->B while R1 is busy); legacy reuses R1 serially.
    char* R1 = ws + 37044224;
    float* maxbuf = (float*)R1;
    float2* buf   = (float2*)R1;
    unsigned short* h_b_fused = (unsigned short*)(ws + 41238528);  // +4 MB, end 45,432,832
    const bool fused = ws_size >= 45432832ull;

    // memset FIRST (sumx accumulated by cvt_all's fused row-sum)
    hipMemsetAsync(ws + 36962304, 0, 81920, stream);
    cvt_all_kernel<<<17024, 256, 0, stream>>>(x, wq, sw1, sw3, sw2, keys, x_b, sumx);
    // q = BN(x @ wq^T + bq) -> bf16 (2048 x 512)
    gemm_nt<0><<<dim3(32, 8), 256, 0, stream>>>(x_b, wq_b, 2048, 512, 768,
                                                nullptr, q_b, bq, gamma, beta, mean, var);
    if (fused) {
        // A: swiglu (512 blocks) + score pass 1 (1024 blocks)
        megaA_kernel<<<1536, 256, 0, stream>>>(x_b, sw1_b, sw3_b, h_b_fused,
                                               q_b, keys_b, maxbuf);
        theta_kernel<<<128, 64, 0, stream>>>(maxbuf, theta);
        // B: down-proj raw -> out (384 blocks) + score pass 2 (1024 blocks)
        megaB_kernel<<<1408, 256, 0, stream>>>(h_b_fused, sw2_b, out,
                                               q_b, keys_b, theta, cnt, buf);
        // top-16 + gates + tiny MLP; adds comb to out rows directly
        finalize_kernel<1><<<2048, 256, 0, stream>>>(cnt, buf, sumx, wdown, wup,
                                                     aw1, aw2, aw3, combsum, out);
    } else {
        // legacy sequence (h_b reuses R1 after finalize)
        unsigned short* h_b = (unsigned short*)R1;
        score_pass_kernel<1><<<1024, 256, 0, stream>>>(q_b, keys_b, maxbuf, nullptr, nullptr, nullptr);
        theta_kernel<<<128, 64, 0, stream>>>(maxbuf, theta);
        score_pass_kernel<2><<<1024, 256, 0, stream>>>(q_b, keys_b, nullptr, theta, cnt, buf);
        finalize_kernel<0><<<2048, 256, 0, stream>>>(cnt, buf, sumx, wdown, wup,
                                                     aw1, aw2, aw3, combsum, nullptr);
        gemm_swiglu_kernel<<<512, 256, 0, stream>>>(x_b, sw1_b, sw3_b, h_b);
        gemm_nt<2><<<dim3(32, 12), 256, 0, stream>>>(h_b, sw2_b, 2048, 768, 1024,
                                                     out, nullptr, combsum,
                                                     nullptr, nullptr, nullptr, nullptr);
    }
}

// Round 11
// 298.939 us; speedup vs baseline: 1.4410x; 1.4410x over previous
//
#include <hip/hip_runtime.h>
#include <hip/hip_bf16.h>
#include <cmath>

// ---------------------------------------------------------------------------
// Problem constants (B=1, T=2048, D=768, H=4, N=25600, KD=128, HQ=512,
// HID_A=44, HID_S=1024, KNN=16)
// ---------------------------------------------------------------------------
#define NEG_INF (-3.402823466e38f)
#define SPLITS 32          // N-splits per head
#define SPN    800         // experts per split
#define GRP    32          // experts per staged LDS group (2 MFMA A-tiles)
#define NGRP   25          // groups per split (800/32)

typedef __attribute__((ext_vector_type(8))) short s16x8;   // 8 bf16 (4 VGPRs)
typedef __attribute__((ext_vector_type(4))) float f32x4;   // MFMA C/D frag

__device__ __forceinline__ unsigned short f2bf(float f) {
    union { float f; unsigned u; } v; v.f = f;
    unsigned u = v.u;
    u += 0x7fffu + ((u >> 16) & 1u);   // round-to-nearest-even
    return (unsigned short)(u >> 16);
}

// ---------------------------------------------------------------------------
// r18: cvt split in two. cvt_small converts {x, wq, sw1, sw3, sw2} (1081344
// float4) + fused row-sum of x; the KEYS conversion moves into megaQ so it
// overlaps the q-projection GEMM (no mutual dependence).
// ---------------------------------------------------------------------------
__global__ __launch_bounds__(256) void cvt_small_kernel(
        const float* __restrict__ s0, const float* __restrict__ s1,
        const float* __restrict__ s2, const float* __restrict__ s3,
        const float* __restrict__ s4,
        unsigned short* __restrict__ dst, float* __restrict__ sumx) {
    int i = blockIdx.x * 256 + threadIdx.x;      // grid 4224 = exact
    const float* src; int base;
    if      (i < 393216)  { src = s0;   base = 0; }
    else if (i < 491520)  { src = s1;   base = 393216; }
    else if (i < 688128)  { src = s2;   base = 491520; }
    else if (i < 884736)  { src = s3;   base = 688128; }
    else                  { src = s4;   base = 884736; }
    float4 f = ((const float4*)src)[i - base];
    ushort4 o;
    o.x = f2bf(f.x); o.y = f2bf(f.y); o.z = f2bf(f.z); o.w = f2bf(f.w);
    ((ushort4*)dst)[i] = o;
    if (i < 393216) {                              // x region: fused row sum
        float s = f.x + f.y + f.z + f.w;
        #pragma unroll
        for (int off = 32; off > 0; off >>= 1) s += __shfl_down(s, off);
        if ((threadIdx.x & 63) == 0) atomicAdd(&sumx[i / 192], s);
    }
}

// ---------------------------------------------------------------------------
// q-projection body: q = BN(x_b @ wq_b^T + bq) -> bf16 (2048 x 512, K=768).
// sb in [0,256): m0=(sb&31)*64, n0=(sb>>5)*64. smem >= 18432 B.
// ---------------------------------------------------------------------------
__device__ __forceinline__ void qproj_body(
        int sb, int tid, const unsigned short* __restrict__ A,
        const unsigned short* __restrict__ W, unsigned short* __restrict__ outB,
        const float* __restrict__ bq, const float* __restrict__ gamma,
        const float* __restrict__ beta, const float* __restrict__ mean,
        const float* __restrict__ var, char* smem) {
    short (*As)[72] = (short(*)[72])smem;             //  9216 B
    short (*Ws)[72] = (short(*)[72])(smem + 9216);    //  9216 B
    const int m0 = (sb & 31) * 64, n0 = (sb >> 5) * 64;
    const int wv = tid >> 6, lane = tid & 63;
    const int wr = wv >> 1, wc = wv & 1;
    const int lr = lane & 15, lq = lane >> 4;
    f32x4 acc[2][2];
    #pragma unroll
    for (int i = 0; i < 2; ++i)
        #pragma unroll
        for (int j = 0; j < 2; ++j) acc[i][j] = (f32x4){0.f, 0.f, 0.f, 0.f};
    for (int kb = 0; kb < 768; kb += 64) {
        #pragma unroll
        for (int it = 0; it < 2; ++it) {
            int chunk = tid + it * 256;
            int row = chunk >> 3, c8 = (chunk & 7) * 8;
            *(s16x8*)&As[row][c8] = *(const s16x8*)(A + (size_t)(m0 + row) * 768 + kb + c8);
            *(s16x8*)&Ws[row][c8] = *(const s16x8*)(W + (size_t)(n0 + row) * 768 + kb + c8);
        }
        __syncthreads();
        #pragma unroll
        for (int ks = 0; ks < 2; ++ks) {
            const int k0 = ks * 32 + lq * 8;
            #pragma unroll
            for (int rt = 0; rt < 2; ++rt) {
                s16x8 a = *(const s16x8*)&As[wr * 32 + rt * 16 + lr][k0];
                #pragma unroll
                for (int ct = 0; ct < 2; ++ct) {
                    s16x8 b = *(const s16x8*)&Ws[wc * 32 + ct * 16 + lr][k0];
                    acc[rt][ct] = __builtin_amdgcn_mfma_f32_16x16x32_bf16(a, b, acc[rt][ct], 0, 0, 0);
                }
            }
        }
        __syncthreads();
    }
    // C/D layout: col = lane&15, row = (lane>>4)*4 + r  [verified m89/m91]
    #pragma unroll
    for (int rt = 0; rt < 2; ++rt)
        #pragma unroll
        for (int ct = 0; ct < 2; ++ct)
            #pragma unroll
            for (int r = 0; r < 4; ++r) {
                int m = m0 + wr * 32 + rt * 16 + lq * 4 + r;
                int n = n0 + wc * 32 + ct * 16 + lr;
                float q = acc[rt][ct][r] + bq[n];
                q = (q - mean[n]) * rsqrtf(var[n] + 1e-5f) * gamma[n] + beta[n];
                outB[(size_t)m * 512 + n] = f2bf(q);
            }
}

// ---------------------------------------------------------------------------
// megaQ: q-proj (256 blocks, first so they start immediately) + keys bf16
// convert (12800 blocks, 3276800 ushort4 exact). The two have no mutual
// dependence; fusion overlaps the 78MB keys traffic with the q-proj GEMM.
// ---------------------------------------------------------------------------
__global__ __launch_bounds__(256) void megaQ_kernel(
        const unsigned short* __restrict__ xb, const unsigned short* __restrict__ wqb,
        unsigned short* __restrict__ qb,
        const float* __restrict__ bq, const float* __restrict__ gamma,
        const float* __restrict__ beta, const float* __restrict__ mean,
        const float* __restrict__ var,
        const float* __restrict__ keys, unsigned short* __restrict__ keys_b) {
    __shared__ alignas(16) char smem[18432];
    if (blockIdx.x < 256) {
        qproj_body(blockIdx.x, threadIdx.x, xb, wqb, qb, bq, gamma, beta,
                   mean, var, smem);
    } else {
        int i = (blockIdx.x - 256) * 256 + threadIdx.x;   // [0, 3276800)
        float4 f = ((const float4*)keys)[i];
        ushort4 o;
        o.x = f2bf(f.x); o.y = f2bf(f.y); o.z = f2bf(f.z); o.w = f2bf(f.w);
        ((ushort4*)keys_b)[i] = o;
    }
}

// ---------------------------------------------------------------------------
// GEMM  C = A @ W^T  (generic, 64x64 tile, BK=64). EPI 2: +combsum[m] -> fp32
// (legacy path only).
// ---------------------------------------------------------------------------
template <int EPI>
__global__ __launch_bounds__(256) void gemm_nt(
        const unsigned short* __restrict__ A, const unsigned short* __restrict__ W,
        int M, int N, int K,
        float* __restrict__ outF, unsigned short* __restrict__ outB,
        const float* __restrict__ p0) {
    __shared__ alignas(16) short As[64][72];
    __shared__ alignas(16) short Ws[64][72];
    const int tid = threadIdx.x;
    const int m0 = blockIdx.x * 64, n0 = blockIdx.y * 64;
    const int wv = tid >> 6, lane = tid & 63;
    const int wr = wv >> 1, wc = wv & 1;
    const int lr = lane & 15, lq = lane >> 4;
    f32x4 acc[2][2];
    #pragma unroll
    for (int i = 0; i < 2; ++i)
        #pragma unroll
        for (int j = 0; j < 2; ++j) acc[i][j] = (f32x4){0.f, 0.f, 0.f, 0.f};

    for (int kb = 0; kb < K; kb += 64) {
        #pragma unroll
        for (int it = 0; it < 2; ++it) {
            int chunk = tid + it * 256;
            int row = chunk >> 3, c8 = (chunk & 7) * 8;
            *(s16x8*)&As[row][c8] = *(const s16x8*)(A + (size_t)(m0 + row) * K + kb + c8);
            *(s16x8*)&Ws[row][c8] = *(const s16x8*)(W + (size_t)(n0 + row) * K + kb + c8);
        }
        __syncthreads();
        #pragma unroll
        for (int ks = 0; ks < 2; ++ks) {
            const int k0 = ks * 32 + lq * 8;
            #pragma unroll
            for (int rt = 0; rt < 2; ++rt) {
                s16x8 a = *(const s16x8*)&As[wr * 32 + rt * 16 + lr][k0];
                #pragma unroll
                for (int ct = 0; ct < 2; ++ct) {
                    s16x8 b = *(const s16x8*)&Ws[wc * 32 + ct * 16 + lr][k0];
                    acc[rt][ct] = __builtin_amdgcn_mfma_f32_16x16x32_bf16(a, b, acc[rt][ct], 0, 0, 0);
                }
            }
        }
        __syncthreads();
    }
    #pragma unroll
    for (int rt = 0; rt < 2; ++rt)
        #pragma unroll
        for (int ct = 0; ct < 2; ++ct)
            #pragma unroll
            for (int r = 0; r < 4; ++r) {
                int m = m0 + wr * 32 + rt * 16 + lq * 4 + r;
                int n = n0 + wc * 32 + ct * 16 + lr;
                outF[(size_t)m * N + n] = acc[rt][ct][r] + p0[m];
            }
}

// ---------------------------------------------------------------------------
// SwiGLU-up body (h = silu(x@W1^T)*(x@W3^T) -> bf16, 2048x1024, K=768).
// sb in [0,512): m0=(sb&31)*64, n0=(sb>>5)*64. smem >= 27648 B.
// ---------------------------------------------------------------------------
__device__ __forceinline__ void swiglu_body(
        int sb, int tid, const unsigned short* __restrict__ A,
        const unsigned short* __restrict__ W1, const unsigned short* __restrict__ W3,
        unsigned short* __restrict__ outB, char* smem) {
    short (*As)[72]  = (short(*)[72])smem;            //  9216 B
    short (*W1s)[72] = (short(*)[72])(smem + 9216);   //  9216 B
    short (*W3s)[72] = (short(*)[72])(smem + 18432);  //  9216 B
    const int m0 = (sb & 31) * 64, n0 = (sb >> 5) * 64;
    const int wv = tid >> 6, lane = tid & 63;
    const int wr = wv >> 1, wc = wv & 1;
    const int lr = lane & 15, lq = lane >> 4;
    f32x4 acc1[2][2], acc3[2][2];
    #pragma unroll
    for (int i = 0; i < 2; ++i)
        #pragma unroll
        for (int j = 0; j < 2; ++j) {
            acc1[i][j] = (f32x4){0.f, 0.f, 0.f, 0.f};
            acc3[i][j] = (f32x4){0.f, 0.f, 0.f, 0.f};
        }
    for (int kb = 0; kb < 768; kb += 64) {
        #pragma unroll
        for (int it = 0; it < 2; ++it) {
            int chunk = tid + it * 256;
            int row = chunk >> 3, c8 = (chunk & 7) * 8;
            *(s16x8*)&As[row][c8]  = *(const s16x8*)(A  + (size_t)(m0 + row) * 768 + kb + c8);
            *(s16x8*)&W1s[row][c8] = *(const s16x8*)(W1 + (size_t)(n0 + row) * 768 + kb + c8);
            *(s16x8*)&W3s[row][c8] = *(const s16x8*)(W3 + (size_t)(n0 + row) * 768 + kb + c8);
        }
        __syncthreads();
        #pragma unroll
        for (int ks = 0; ks < 2; ++ks) {
            const int k0 = ks * 32 + lq * 8;
            #pragma unroll
            for (int rt = 0; rt < 2; ++rt) {
                s16x8 a = *(const s16x8*)&As[wr * 32 + rt * 16 + lr][k0];
                #pragma unroll
                for (int ct = 0; ct < 2; ++ct) {
                    s16x8 b1 = *(const s16x8*)&W1s[wc * 32 + ct * 16 + lr][k0];
                    s16x8 b3 = *(const s16x8*)&W3s[wc * 32 + ct * 16 + lr][k0];
                    acc1[rt][ct] = __builtin_amdgcn_mfma_f32_16x16x32_bf16(a, b1, acc1[rt][ct], 0, 0, 0);
                    acc3[rt][ct] = __builtin_amdgcn_mfma_f32_16x16x32_bf16(a, b3, acc3[rt][ct], 0, 0, 0);
                }
            }
        }
        __syncthreads();
    }
    #pragma unroll
    for (int rt = 0; rt < 2; ++rt)
        #pragma unroll
        for (int ct = 0; ct < 2; ++ct)
            #pragma unroll
            for (int r = 0; r < 4; ++r) {
                int m = m0 + wr * 32 + rt * 16 + lq * 4 + r;
                int n = n0 + wc * 32 + ct * 16 + lr;
                float u1 = acc1[rt][ct][r], u3 = acc3[rt][ct][r];
                float hv = u1 / (1.f + expf(-u1)) * u3;
                outB[(size_t)m * 1024 + n] = f2bf(hv);
            }
}

// ---------------------------------------------------------------------------
// Down-proj body, RAW (out = h @ W2^T, 2048x768, K=1024; combsum added later
// by finalize_out). sb in [0,384): m0=(sb&31)*64, n0=(sb>>5)*64. smem>=18432.
// ---------------------------------------------------------------------------
__device__ __forceinline__ void down_body(
        int sb, int tid, const unsigned short* __restrict__ A,
        const unsigned short* __restrict__ W, float* __restrict__ outF,
        char* smem) {
    short (*As)[72] = (short(*)[72])smem;             //  9216 B
    short (*Ws)[72] = (short(*)[72])(smem + 9216);    //  9216 B
    const int m0 = (sb & 31) * 64, n0 = (sb >> 5) * 64;
    const int wv = tid >> 6, lane = tid & 63;
    const int wr = wv >> 1, wc = wv & 1;
    const int lr = lane & 15, lq = lane >> 4;
    f32x4 acc[2][2];
    #pragma unroll
    for (int i = 0; i < 2; ++i)
        #pragma unroll
        for (int j = 0; j < 2; ++j) acc[i][j] = (f32x4){0.f, 0.f, 0.f, 0.f};
    for (int kb = 0; kb < 1024; kb += 64) {
        #pragma unroll
        for (int it = 0; it < 2; ++it) {
            int chunk = tid + it * 256;
            int row = chunk >> 3, c8 = (chunk & 7) * 8;
            *(s16x8*)&As[row][c8] = *(const s16x8*)(A + (size_t)(m0 + row) * 1024 + kb + c8);
            *(s16x8*)&Ws[row][c8] = *(const s16x8*)(W + (size_t)(n0 + row) * 1024 + kb + c8);
        }
        __syncthreads();
        #pragma unroll
        for (int ks = 0; ks < 2; ++ks) {
            const int k0 = ks * 32 + lq * 8;
            #pragma unroll
            for (int rt = 0; rt < 2; ++rt) {
                s16x8 a = *(const s16x8*)&As[wr * 32 + rt * 16 + lr][k0];
                #pragma unroll
                for (int ct = 0; ct < 2; ++ct) {
                    s16x8 b = *(const s16x8*)&Ws[wc * 32 + ct * 16 + lr][k0];
                    acc[rt][ct] = __builtin_amdgcn_mfma_f32_16x16x32_bf16(a, b, acc[rt][ct], 0, 0, 0);
                }
            }
        }
        __syncthreads();
    }
    #pragma unroll
    for (int rt = 0; rt < 2; ++rt)
        #pragma unroll
        for (int ct = 0; ct < 2; ++ct)
            #pragma unroll
            for (int r = 0; r < 4; ++r) {
                int m = m0 + wr * 32 + rt * 16 + lq * 4 + r;
                int n = n0 + wc * 32 + ct * 16 + lr;
                outF[(size_t)m * 768 + n] = acc[rt][ct][r];
            }
}

// ---------------------------------------------------------------------------
// Score-pass body — EXACT r4/r15 anchor (74.7 us standalone, 82 us in mega;
// the session's verified best). GRP=32/tt=4 LDS-staged with one-group
// register prefetch is LOAD-BEARING:
//   GRP=64 (r9/r14), tt=2 (r10/r12/r13), direct-global (r16), direct+pingpong
//   (r17) ALL regressed. Do not touch.
// b in [0,1024). smem >= 17408 B.
// PASS 1: per-(lane,token) running max -> maxbuf[8192][128] (cell=(sp,lq)).
// PASS 2: recompute, compact (v,idx) >= theta[t,h] via atomicAdd, cap 64.
// ---------------------------------------------------------------------------
template <int PASS>
__device__ __forceinline__ void score_body(
        int b, int tid,
        const unsigned short* __restrict__ Q, const unsigned short* __restrict__ Kt,
        float* __restrict__ maxbuf, const float* __restrict__ theta,
        int* __restrict__ cnt, float2* __restrict__ buf, char* smem) {
    short (*Ks)[GRP][136] = (short(*)[GRP][136])smem;   // [2][32][136]
    const int tile = b >> 7;                     // 128 = 4 heads x 32 splits
    const int hsp = b & 127;
    const int h = hsp >> 5, sp = hsp & 31;
    const int w = tid >> 6, lane = tid & 63;
    const int lr = lane & 15, lq = lane >> 4;
    const int t0 = tile * 256 + w * 64;
    const int nb0 = sp * SPN;

    s16x8 qf[4][4];
    #pragma unroll
    for (int tt = 0; tt < 4; ++tt) {
        const unsigned short* qp = Q + (size_t)(t0 + tt * 16 + lr) * 512 + h * 128 + lq * 8;
        #pragma unroll
        for (int ks = 0; ks < 4; ++ks) qf[tt][ks] = *(const s16x8*)(qp + ks * 32);
    }

    float runmax[4] = {NEG_INF, NEG_INF, NEG_INF, NEG_INF};
    float th[4];
    if (PASS == 2) {
        #pragma unroll
        for (int tt = 0; tt < 4; ++tt) th[tt] = theta[(t0 + tt * 16 + lr) * 4 + h];
    }

    const int srow = tid >> 4;                   // 0..15
    const int scol = (tid & 15) * 8;             // bf16 elem 0..120
    const unsigned short* kgp =
        Kt + ((size_t)h * 25600 + nb0 + srow) * 128 + scol;

    {   // prologue: stage group 0 into buffer 0
        *(s16x8*)&Ks[0][srow][scol]      = *(const s16x8*)kgp;
        *(s16x8*)&Ks[0][srow + 16][scol] = *(const s16x8*)(kgp + 2048);
    }

    for (int g = 0; g < NGRP; ++g) {
        s16x8 ka0, ka1;
        if (g + 1 < NGRP) {
            const unsigned short* kp = kgp + (size_t)(g + 1) * 4096;
            ka0 = *(const s16x8*)kp;
            ka1 = *(const s16x8*)(kp + 2048);
        }
        __syncthreads();
        const int cb = g & 1;
        #pragma unroll
        for (int st = 0; st < 2; ++st) {
            f32x4 acc[4];
            #pragma unroll
            for (int tt = 0; tt < 4; ++tt) acc[tt] = (f32x4){0.f, 0.f, 0.f, 0.f};
            #pragma unroll
            for (int ks = 0; ks < 4; ++ks) {
                s16x8 ka = *(const s16x8*)&Ks[cb][st * 16 + lr][ks * 32 + lq * 8];
                #pragma unroll
                for (int tt = 0; tt < 4; ++tt)
                    acc[tt] = __builtin_amdgcn_mfma_f32_16x16x32_bf16(ka, qf[tt][ks], acc[tt], 0, 0, 0);
            }
            if (PASS == 1) {
                #pragma unroll
                for (int tt = 0; tt < 4; ++tt) {
                    float m0 = fmaxf(fmaxf(acc[tt][0], acc[tt][1]),
                                     fmaxf(acc[tt][2], acc[tt][3]));
                    runmax[tt] = fmaxf(runmax[tt], m0);
                }
            } else {
                const int nb = nb0 + g * GRP + st * 16;
                #pragma unroll
                for (int tt = 0; tt < 4; ++tt) {
                    float m0 = fmaxf(fmaxf(acc[tt][0], acc[tt][1]),
                                     fmaxf(acc[tt][2], acc[tt][3]));
                    if (m0 >= th[tt]) {
                        int g4 = (t0 + tt * 16 + lr) * 4 + h;
                        #pragma unroll
                        for (int r = 0; r < 4; ++r) {
                            if (acc[tt][r] >= th[tt]) {
                                int n = nb + lq * 4 + r;   // D row = lq*4+r
                                int pos = atomicAdd(&cnt[g4], 1);
                                if (pos < 64) {
                                    float2 e; e.x = acc[tt][r]; e.y = __int_as_float(n);
                                    buf[(size_t)g4 * 64 + pos] = e;
                                }
                            }
                        }
                    }
                }
            }
        }
        if (g + 1 < NGRP) {
            const int nbuf = cb ^ 1;
            *(s16x8*)&Ks[nbuf][srow][scol]      = ka0;
            *(s16x8*)&Ks[nbuf][srow + 16][scol] = ka1;
        }
    }

    if (PASS == 1) {
        #pragma unroll
        for (int tt = 0; tt < 4; ++tt)
            maxbuf[(size_t)((t0 + tt * 16 + lr) * 4 + h) * 128 + sp * 4 + lq] = runmax[tt];
    }
}

// ---------------------------------------------------------------------------
// Standalone score pass (legacy path).
// ---------------------------------------------------------------------------
template <int PASS>
__global__ __launch_bounds__(256, 4) void score_pass_kernel(
        const unsigned short* __restrict__ Q, const unsigned short* __restrict__ Kt,
        float* __restrict__ maxbuf, const float* __restrict__ theta,
        int* __restrict__ cnt, float2* __restrict__ buf) {
    __shared__ alignas(16) char smem[17408];
    score_body<PASS>(blockIdx.x, threadIdx.x, Q, Kt, maxbuf, theta, cnt, buf, smem);
}

// ---------------------------------------------------------------------------
// Fused mega-kernels: dense-GEMM blocks FIRST (concurrent mix from t=0),
// score blocks after. Offsets 512/384 are =0 mod 8, so score blocks keep
// their slab->XCD co-location (slab stride 128 = 0 mod 8).
// ---------------------------------------------------------------------------
__global__ __launch_bounds__(256, 4) void megaA_kernel(   // swiglu(512) + score1(1024)
        const unsigned short* __restrict__ xb, const unsigned short* __restrict__ w1,
        const unsigned short* __restrict__ w3, unsigned short* __restrict__ hb,
        const unsigned short* __restrict__ Q, const unsigned short* __restrict__ Kt,
        float* __restrict__ maxbuf) {
    __shared__ alignas(16) char smem[27648];
    if (blockIdx.x < 512)
        swiglu_body(blockIdx.x, threadIdx.x, xb, w1, w3, hb, smem);
    else
        score_body<1>(blockIdx.x - 512, threadIdx.x, Q, Kt, maxbuf,
                      nullptr, nullptr, nullptr, smem);
}

__global__ __launch_bounds__(256, 4) void megaB_kernel(   // down(384) + score2(1024)
        const unsigned short* __restrict__ hb, const unsigned short* __restrict__ w2,
        float* __restrict__ outF,
        const unsigned short* __restrict__ Q, const unsigned short* __restrict__ Kt,
        const float* __restrict__ theta, int* __restrict__ cnt,
        float2* __restrict__ buf) {
    __shared__ alignas(16) char smem[18432];
    if (blockIdx.x < 384)
        down_body(blockIdx.x, threadIdx.x, hb, w2, outF, smem);
    else
        score_body<2>(blockIdx.x - 384, threadIdx.x, Q, Kt, nullptr,
                      theta, cnt, buf, smem);
}

// ---------------------------------------------------------------------------
// theta = 16th-largest of the 128 cell maxima per (t,h).
// ---------------------------------------------------------------------------
__global__ __launch_bounds__(64) void theta_kernel(
        const float* __restrict__ maxbuf, float* __restrict__ theta) {
    int g = blockIdx.x * 64 + threadIdx.x;
    if (g >= 8192) return;
    const float* mb = maxbuf + (size_t)g * 128;
    float s[16];
    #pragma unroll
    for (int i = 0; i < 16; ++i) s[i] = NEG_INF;
    for (int j = 0; j < 128; ++j) {
        float v = mb[j];
        if (v > s[15]) {
            #pragma unroll
            for (int i = 15; i > 0; --i)
                s[i] = (v > s[i - 1]) ? s[i - 1] : ((v > s[i]) ? v : s[i]);
            s[0] = (v > s[0]) ? v : s[0];
        }
    }
    theta[g] = s[15];
}

// ---------------------------------------------------------------------------
// Finalize. Block = token t (4 waves = 4 heads). Exact top-16 via rank,
// softmax, tiny MLP (reassociated). FUSE_OUT=1: block-reduce 4 head contribs
// and add to out[t][:] (out holds raw down-proj). FUSE_OUT=0: legacy.
// ---------------------------------------------------------------------------
template <int FUSE_OUT>
__global__ __launch_bounds__(256) void finalize_kernel(
        const int* __restrict__ cnt, const float2* __restrict__ buf,
        const float* __restrict__ sumx,
        const float* __restrict__ wdown, const float* __restrict__ wup,
        const float* __restrict__ aw1, const float* __restrict__ aw2,
        const float* __restrict__ aw3, float* __restrict__ combsum,
        float* __restrict__ out) {
    __shared__ float zsh[4][16];
    __shared__ float wsh[4][16];
    __shared__ float csh[4];
    const int wv = threadIdx.x >> 6, lane = threadIdx.x & 63;
    const int t = blockIdx.x;
    const int g = t * 4 + wv;
    int c = cnt[g]; c = (c > 64) ? 64 : c;       // >=16 guaranteed by theta

    float v = NEG_INF; int n = 0x7fffffff;
    if (lane < c) {
        float2 e = buf[(size_t)g * 64 + lane];
        v = e.x; n = __float_as_int(e.y);
    }
    int r = 0;
    for (int i = 0; i < c; ++i) {
        float vi = __shfl(v, i);
        int   ni = __shfl(n, i);
        r += ((vi > v) || (vi == v && ni < n)) ? 1 : 0;
    }
    float m = v;
    #pragma unroll
    for (int off = 32; off > 0; off >>= 1) m = fmaxf(m, __shfl_xor(m, off));
    const bool sel = (lane < c) && (r < 16);
    float e = sel ? expf(v - m) : 0.f;
    float den = e;
    #pragma unroll
    for (int off = 32; off > 0; off >>= 1) den += __shfl_xor(den, off);
    if (sel) {
        zsh[wv][r] = sumx[t] * wdown[n];
        wsh[wv][r] = (e / den) * wup[n];
    }
    __syncthreads();
    float contrib = 0.f;
    if (lane < 44) {
        float u1 = 0.f, u3 = 0.f, cj = 0.f;
        #pragma unroll
        for (int k = 0; k < 16; ++k) {
            float zk = zsh[wv][k];
            u1 += zk * aw1[lane * 16 + k];
            u3 += zk * aw3[lane * 16 + k];
            cj += wsh[wv][k] * aw2[k * 44 + lane];
        }
        float gj = u1 / (1.f + expf(-u1)) * u3;
        contrib = gj * cj;
    }
    #pragma unroll
    for (int off = 32; off > 0; off >>= 1) contrib += __shfl_xor(contrib, off);
    if (FUSE_OUT) {
        if (lane == 0) csh[wv] = contrib;
        __syncthreads();
        float comb = csh[0] + csh[1] + csh[2] + csh[3];
        float* orow = out + (size_t)t * 768;
        #pragma unroll
        for (int i = 0; i < 3; ++i) orow[threadIdx.x + i * 256] += comb;
    } else {
        if (lane == 0) atomicAdd(&combsum[t], contrib);
    }
}

// ---------------------------------------------------------------------------
// Legacy standalone SwiGLU (fallback path).
// ---------------------------------------------------------------------------
__global__ __launch_bounds__(256) void gemm_swiglu_kernel(
        const unsigned short* __restrict__ A, const unsigned short* __restrict__ W1,
        const unsigned short* __restrict__ W3, unsigned short* __restrict__ outB) {
    __shared__ alignas(16) char smem[27648];
    swiglu_body(blockIdx.x, threadIdx.x, A, W1, W3, outB, smem);
}

// ---------------------------------------------------------------------------
// Host launch
// ---------------------------------------------------------------------------
extern "C" void kernel_launch(void* const* d_in, const int* in_sizes, int n_in,
                              void* d_out, int out_size, void* d_ws, size_t ws_size,
                              hipStream_t stream) {
    const float* x     = (const float*)d_in[0];
    const float* wq    = (const float*)d_in[1];
    const float* bq    = (const float*)d_in[2];
    const float* gamma = (const float*)d_in[3];
    const float* beta  = (const float*)d_in[4];
    const float* mean  = (const float*)d_in[5];
    const float* var   = (const float*)d_in[6];
    const float* keys  = (const float*)d_in[7];
    const float* wdown = (const float*)d_in[8];
    const float* wup   = (const float*)d_in[9];
    const float* aw1   = (const float*)d_in[10];
    const float* aw2   = (const float*)d_in[11];
    const float* aw3   = (const float*)d_in[12];
    const float* sw1   = (const float*)d_in[13];
    const float* sw2   = (const float*)d_in[14];
    const float* sw3   = (const float*)d_in[15];
    float* out = (float*)d_out;

    char* ws = (char*)d_ws;
    unsigned short* x_b    = (unsigned short*)(ws + 0);         // 3,145,728 B
    unsigned short* wq_b   = (unsigned short*)(ws + 3145728);   //   786,432
    unsigned short* sw1_b  = (unsigned short*)(ws + 3932160);   // 1,572,864
    unsigned short* sw3_b  = (unsigned short*)(ws + 5505024);   // 1,572,864
    unsigned short* sw2_b  = (unsigned short*)(ws + 7077888);   // 1,572,864
    unsigned short* keys_b = (unsigned short*)(ws + 8650752);   // 26,214,400
    unsigned short* q_b    = (unsigned short*)(ws + 34865152);  // 2,097,152
    float* sumx    = (float*)(ws + 36962304);                   //     8,192 }
    float* theta   = (float*)(ws + 36970496);                   //    32,768 } one
    float* combsum = (float*)(ws + 37003264);                   //     8,192 } memset
    int*   cnt     = (int*)  (ws + 37011456);                   //    32,768 }
    // R1 (4 MB): maxbuf (A-phase) -> buf (B-phase). h_b separate in fused
    // path (lives across A->B while R1 is busy); legacy reuses R1 serially.
    char* R1 = ws + 37044224;
    float* maxbuf = (float*)R1;
    float2* buf   = (float2*)R1;
    unsigned short* h_b_fused = (unsigned short*)(ws + 41238528);  // +4 MB, end 45,432,832
    const bool fused = ws_size >= 45432832ull;

    // memset FIRST (sumx accumulated by cvt_small's fused row-sum)
    hipMemsetAsync(ws + 36962304, 0, 81920, stream);
    // small tensors (x, wq, sw1, sw3, sw2) -> bf16 + row-sum of x
    cvt_small_kernel<<<4224, 256, 0, stream>>>(x, wq, sw1, sw3, sw2, x_b, sumx);
    // q-proj GEMM (256 blocks) overlapped with keys bf16 convert (12800 blocks)
    megaQ_kernel<<<13056, 256, 0, stream>>>(x_b, wq_b, q_b, bq, gamma, beta,
                                            mean, var, keys, keys_b);
    if (fused) {
        // A: swiglu (512 blocks) + score pass 1 (1024 blocks)
        megaA_kernel<<<1536, 256, 0, stream>>>(x_b, sw1_b, sw3_b, h_b_fused,
                                               q_b, keys_b, maxbuf);
        theta_kernel<<<128, 64, 0, stream>>>(maxbuf, theta);
        // B: down-proj raw -> out (384 blocks) + score pass 2 (1024 blocks)
        megaB_kernel<<<1408, 256, 0, stream>>>(h_b_fused, sw2_b, out,
                                               q_b, keys_b, theta, cnt, buf);
        // top-16 + gates + tiny MLP; adds comb to out rows directly
        finalize_kernel<1><<<2048, 256, 0, stream>>>(cnt, buf, sumx, wdown, wup,
                                                     aw1, aw2, aw3, combsum, out);
    } else {
        // legacy sequence (h_b reuses R1 after finalize)
        unsigned short* h_b = (unsigned short*)R1;
        score_pass_kernel<1><<<1024, 256, 0, stream>>>(q_b, keys_b, maxbuf, nullptr, nullptr, nullptr);
        theta_kernel<<<128, 64, 0, stream>>>(maxbuf, theta);
        score_pass_kernel<2><<<1024, 256, 0, stream>>>(q_b, keys_b, nullptr, theta, cnt, buf);
        finalize_kernel<0><<<2048, 256, 0, stream>>>(cnt, buf, sumx, wdown, wup,
                                                     aw1, aw2, aw3, combsum, nullptr);
        gemm_swiglu_kernel<<<512, 256, 0, stream>>>(x_b, sw1_b, sw3_b, h_b);
        gemm_nt<2><<<dim3(32, 12), 256, 0, stream>>>(h_b, sw2_b, 2048, 768, 1024,
                                                     out, nullptr, combsum);
    }
}